// Round 15
// baseline (496.168 us; speedup 1.0000x reference)
//
#include <hip/hip_runtime.h>
#include <hip/hip_bf16.h>
#include <stdint.h>

#define BATCH_N 65536
#define KDIM 1024
#define NTOT 1536

typedef __bf16 bf16x8 __attribute__((ext_vector_type(8)));
typedef float f32x4 __attribute__((ext_vector_type(4)));

__device__ __forceinline__ unsigned short f2bf(float f) {
    unsigned u = __builtin_bit_cast(unsigned, f);
    u += 0x7FFFu + ((u >> 16) & 1u);   // round-to-nearest-even
    return (unsigned short)(u >> 16);
}

// ---------------------------------------------------------------------------
// Kernel 1: x[b][k] = sum(node_memories[id]) + node_embedding[id][k], bf16,
// pre-swizzled (k ^= (b&7)<<3).  One WAVE per row; each lane owns 4 float4
// chunks at k = q*256 + lane*4, butterfly reduce.
// ---------------------------------------------------------------------------
__global__ __launch_bounds__(256) void prep_kernel(
    const int* __restrict__ ids,
    const float* __restrict__ mem,
    const float* __restrict__ emb,
    unsigned short* __restrict__ x)
{
    const int b    = blockIdx.x * 4 + (threadIdx.x >> 6);
    const int lane = threadIdx.x & 63;
    const int id   = ids[b];
    const float4* m4 = (const float4*)(mem + (size_t)id * KDIM) + lane;
    const float4* e4 = (const float4*)(emb + (size_t)id * KDIM) + lane;
    float4 v0 = m4[0];
    float4 v1 = m4[64];
    float4 v2 = m4[128];
    float4 v3 = m4[192];
    float s = (v0.x + v0.y + v0.z + v0.w) + (v1.x + v1.y + v1.z + v1.w)
            + (v2.x + v2.y + v2.z + v2.w) + (v3.x + v3.y + v3.z + v3.w);
    #pragma unroll
    for (int off = 1; off < 64; off <<= 1) s += __shfl_xor(s, off, 64);
    unsigned short* xb = x + (size_t)b * KDIM;
    #pragma unroll
    for (int q = 0; q < 4; ++q) {
        float4 e = e4[q * 64];
        ushort4 o;
        o.x = f2bf(s + e.x);
        o.y = f2bf(s + e.y);
        o.z = f2bf(s + e.z);
        o.w = f2bf(s + e.w);
        const int k   = q * 256 + lane * 4;
        const int ksw = k ^ ((b & 7) << 3);
        *(ushort4*)(xb + ksw) = o;
    }
}

// ---------------------------------------------------------------------------
// Kernel 2: Wt[n][k] = W_{n/512}[k][n%512] in bf16, same pre-swizzle on k.
// ---------------------------------------------------------------------------
__global__ __launch_bounds__(256) void wconv_kernel(
    const float* __restrict__ Wq, const float* __restrict__ Ws,
    const float* __restrict__ Wk, unsigned short* __restrict__ wt)
{
    const int gt = blockIdx.x * 256 + threadIdx.x;   // 0..393215
    const int n  = gt % NTOT;
    const int kb = (gt / NTOT) * 4;
    const float* W = (n < 512) ? Wq : ((n < 1024) ? Ws : Wk);
    const int nn = n & 511;
    ushort4 o;
    o.x = f2bf(W[(size_t)(kb + 0) * 512 + nn]);
    o.y = f2bf(W[(size_t)(kb + 1) * 512 + nn]);
    o.z = f2bf(W[(size_t)(kb + 2) * 512 + nn]);
    o.w = f2bf(W[(size_t)(kb + 3) * 512 + nn]);
    const int ksw = kb ^ ((n & 7) << 3);
    *(ushort4*)(wt + (size_t)n * KDIM + ksw) = o;
}

// ---------------------------------------------------------------------------
// Kernel 3: 256x256 GEMM, 4 waves (2M x 2N), PER-WAVE 128x128 output.
//   Rationale (r14 post-mortem): the 8-wave 2Mx4N split re-read each A-frag
//   4x from LDS -> DS pipe (384 KB/pair) > MFMA (512 cyc/phase) -> DS-bound.
//   128x128/wave cuts LDS reads to 32 b128/wave/tile (128 KB/tile block-wide)
//   while per-SIMD MFMA rises to 2048 cyc/tile (1 wave/SIMD) -> MFMA-bound.
//   acc = 256 f32/lane (unified VGPR/AGPR file), bfr = 16 bf16x8, af rolls.
//   Schedule (1 barrier/tile): per tile t (slot s=t&1):
//     STG(tile t+1 -> slot s^1)  [8 DMA, ~2000 cyc lead over its VM0]
//     16 bfr ds_reads; af[0..1]; for mf=0..7 { af[mf+2] in shadow; 16 MFMA }
//     VM0 (DMA long since landed) ; BAR  (slot swap)
//   RAW: tile t+1 reads open behind VM0+BAR (outstanding VMEM=0 at boundary).
//   WAR: slot s^1's last reads (tile t-1) were consumed by MFMAs before
//   BAR(t-1), which precedes this STG.
// ---------------------------------------------------------------------------
#define BM 256
#define BN 256
#define BK 64
#define MT (BATCH_N / BM)   // 256
#define NT (NTOT / BN)      // 6
#define NWG (MT * NT)       // 1536 = 8 * 192, 192 % 6 == 0 -> bijective

#define BAR() asm volatile("s_barrier" ::: "memory")
#define VM0() asm volatile("s_waitcnt vmcnt(0)" ::: "memory")
#define AS1 __attribute__((address_space(1)))
#define AS3 __attribute__((address_space(3)))

__global__ __launch_bounds__(256, 1) void gemm_kernel(
    const unsigned short* __restrict__ X,    // [65536][1024] bf16, swizzled
    const unsigned short* __restrict__ Wt,   // [1536][1024]  bf16, swizzled
    const float* __restrict__ bq, const float* __restrict__ bs,
    const float* __restrict__ bk, float* __restrict__ out)
{
    __shared__ __align__(16) unsigned short sA[2 * 16384];   // 2 slots x 32 KiB
    __shared__ __align__(16) unsigned short sB[2 * 16384];

    const int tid  = threadIdx.x;
    const int xcd  = blockIdx.x & 7;
    const int idx  = blockIdx.x >> 3;
    const int wgid = xcd * (NWG / 8) + idx;
    const int nt   = wgid % NT;              // n fastest: A-panel L2 reuse
    const int mt   = wgid / NT;
    const int m0   = mt * BM;
    const int n0   = nt * BN;
    const int wid  = tid >> 6;
    const int lane = tid & 63;
    const int wm   = wid >> 1;               // 0..1
    const int wn   = wid & 1;                // 0..1
    const int r16  = lane & 15;
    const int kb0  = (lane >> 4) << 4;       // 0,16,32,48 (bytes)
    const int ksw  = (r16 & 7) << 4;         // LDS XOR swizzle (bytes)

    f32x4 acc[8][8];                         // 256 f32/lane
    #pragma unroll
    for (int i = 0; i < 8; i++)
        #pragma unroll
        for (int j = 0; j < 8; j++)
            acc[i][j] = f32x4{0.f, 0.f, 0.f, 0.f};

    bf16x8 af[8][2], bfr[8][2];

    const unsigned short* gA = X  + (size_t)(m0 + (tid >> 3)) * KDIM + (tid & 7) * 8;
    const unsigned short* gB = Wt + (size_t)(n0 + (tid >> 3)) * KDIM + (tid & 7) * 8;
    const int ldst = (tid & 192) * 8;        // wave-uniform LDS elem offset (wave*1KB)

// stage a full 256x64 operand tile (8 DMA instrs/thread, 32 rows each)
#define STG_A(slot, kt) do {                                                    \
    _Pragma("unroll")                                                            \
    for (int c = 0; c < 8; ++c)                                                  \
        __builtin_amdgcn_global_load_lds(                                        \
            (const AS1 void*)(gA + (size_t)(c) * 32 * KDIM + (kt) * BK),         \
            (AS3 void*)(&sA[(slot) * 16384 + (c) * 2048 + ldst]), 16, 0, 0);     \
} while (0)
#define STG_B(slot, kt) do {                                                    \
    _Pragma("unroll")                                                            \
    for (int c = 0; c < 8; ++c)                                                  \
        __builtin_amdgcn_global_load_lds(                                        \
            (const AS1 void*)(gB + (size_t)(c) * 32 * KDIM + (kt) * BK),         \
            (AS3 void*)(&sB[(slot) * 16384 + (c) * 2048 + ldst]), 16, 0, 0);     \
} while (0)

#define LDA1(slot, mf) do {                                                     \
    const char* p = (const char*)&sA[(slot) * 16384];                            \
    _Pragma("unroll")                                                            \
    for (int kk = 0; kk < 2; ++kk)                                               \
        af[mf][kk] = *(const bf16x8*)(p + (wm * 128 + (mf) * 16 + r16) * 128     \
                                        + ((kk * 64 + kb0) ^ ksw));              \
} while (0)
#define LDB_ALL(slot) do {                                                      \
    const char* p = (const char*)&sB[(slot) * 16384];                            \
    _Pragma("unroll")                                                            \
    for (int jf = 0; jf < 8; ++jf)                                               \
        _Pragma("unroll")                                                        \
        for (int kk = 0; kk < 2; ++kk)                                           \
            bfr[jf][kk] = *(const bf16x8*)(p + (wn * 128 + jf * 16 + r16) * 128  \
                                             + ((kk * 64 + kb0) ^ ksw));         \
} while (0)

#define MMROW(mf) do {                                                          \
    _Pragma("unroll")                                                            \
    for (int jf = 0; jf < 8; ++jf)                                               \
        _Pragma("unroll")                                                        \
        for (int kk = 0; kk < 2; ++kk)                                           \
            acc[mf][jf] = __builtin_amdgcn_mfma_f32_16x16x32_bf16(               \
                af[mf][kk], bfr[jf][kk], acc[mf][jf], 0, 0, 0);                  \
} while (0)

// one K-tile: stage next into other slot first, then pipelined read+compute
#define TILE(S, KTN, DOSTAGE) do {                                              \
    if (DOSTAGE) { STG_A((S) ^ 1, KTN); STG_B((S) ^ 1, KTN); }                   \
    LDB_ALL(S);                                                                  \
    LDA1(S, 0); LDA1(S, 1);                                                      \
    LDA1(S, 2); MMROW(0);                                                        \
    LDA1(S, 3); MMROW(1);                                                        \
    LDA1(S, 4); MMROW(2);                                                        \
    LDA1(S, 5); MMROW(3);                                                        \
    LDA1(S, 6); MMROW(4);                                                        \
    LDA1(S, 7); MMROW(5);                                                        \
    MMROW(6); MMROW(7);                                                          \
    VM0(); BAR();                                                                \
} while (0)

    // ---- prologue: stage tile0 into slot0 ----
    STG_A(0, 0); STG_B(0, 0);
    VM0();
    BAR();

    // ---- main loop ----
    #pragma unroll 1
    for (int t = 0; t < 7; ++t) {
        TILE(0, 2 * t + 1, 1);
        TILE(1, 2 * t + 2, 1);
    }
    TILE(0, 15, 1);
    TILE(1, 0, 0);

    // ---- epilogue: bias + sigmoid, nontemporal fp32 stores ----
    // C/D layout: col=lane&15, row=(lane>>4)*4+reg  [m89/m91]
    const int grp = nt >> 1;                        // 0=q, 1=s, 2=k
    const float* bias = (grp == 0) ? bq : ((grp == 1) ? bs : bk);
    float* obase = out + (size_t)grp * ((size_t)BATCH_N * 512);
    const int cb = (nt & 1) * 256;
    #pragma unroll
    for (int jf = 0; jf < 8; ++jf) {
        const int col = cb + wn * 128 + jf * 16 + r16;
        const float bv = bias[col];
        #pragma unroll
        for (int mf = 0; mf < 8; ++mf) {
            const int rbase = m0 + wm * 128 + mf * 16 + ((lane >> 4) << 2);
            #pragma unroll
            for (int r = 0; r < 4; ++r) {
                float v = acc[mf][jf][r] + bv;
                v = 1.0f / (1.0f + __expf(-v));
                __builtin_nontemporal_store(v, &obase[(size_t)(rbase + r) * 512 + col]);
            }
        }
    }
#undef STG_A
#undef STG_B
#undef LDA1
#undef LDB_ALL
#undef MMROW
#undef TILE
}

extern "C" void kernel_launch(void* const* d_in, const int* in_sizes, int n_in,
                              void* d_out, int out_size, void* d_ws, size_t ws_size,
                              hipStream_t stream) {
    const int*   ids = (const int*)d_in[0];
    const float* mem = (const float*)d_in[1];
    const float* emb = (const float*)d_in[2];
    const float* Wq  = (const float*)d_in[3];
    const float* bq  = (const float*)d_in[4];
    const float* Ws  = (const float*)d_in[5];
    const float* bs  = (const float*)d_in[6];
    const float* Wk  = (const float*)d_in[7];
    const float* bk  = (const float*)d_in[8];
    float* out = (float*)d_out;

    unsigned short* x  = (unsigned short*)d_ws;              // 65536*1024 bf16 = 128 MiB
    unsigned short* wt = x + (size_t)BATCH_N * KDIM;         // 1536*1024  bf16 = 3 MiB

    hipLaunchKernelGGL(wconv_kernel, dim3(NTOT), dim3(256), 0, stream, Wq, Ws, Wk, wt);
    hipLaunchKernelGGL(prep_kernel, dim3(BATCH_N / 4), dim3(256), 0, stream, ids, mem, emb, x);
    hipLaunchKernelGGL(gemm_kernel, dim3(NWG), dim3(256), 0, stream,
                       x, wt, bq, bs, bk, out);
}

// Round 16
// 394.340 us; speedup vs baseline: 1.2582x; 1.2582x over previous
//
#include <hip/hip_runtime.h>
#include <hip/hip_bf16.h>
#include <stdint.h>

#define BATCH_N 65536
#define KDIM 1024
#define NTOT 1536

typedef long long i64;
typedef float f32x4 __attribute__((ext_vector_type(4)));

// pack 4 floats (scaled) into 4 fp8-e4m3 bytes
__device__ __forceinline__ unsigned pk4(float4 f, float s) {
    int w = __builtin_amdgcn_cvt_pk_fp8_f32(f.x * s, f.y * s, 0, false);
    w = __builtin_amdgcn_cvt_pk_fp8_f32(f.z * s, f.w * s, w, true);
    return (unsigned)w;
}

// ---------------------------------------------------------------------------
// Kernel 1: E[b][k] = emb[id_b][k] * 64 in fp8 e4m3, pre-swizzled
// (byte pos p holds E[p ^ ((b&7)<<3)]); rs[b] = rowsum(mem[id_b]) fp32.
// One WAVE per row: lane owns k = lane*16..+16 for E; butterfly for rowsum.
// ---------------------------------------------------------------------------
__global__ __launch_bounds__(256) void prep_kernel(
    const int* __restrict__ ids,
    const float* __restrict__ mem,
    const float* __restrict__ emb,
    unsigned char* __restrict__ x,
    float* __restrict__ rs)
{
    const int b    = blockIdx.x * 4 + (threadIdx.x >> 6);
    const int lane = threadIdx.x & 63;
    const int id   = ids[b];
    const float4* m4 = (const float4*)(mem + (size_t)id * KDIM) + lane;
    float4 v0 = m4[0], v1 = m4[64], v2 = m4[128], v3 = m4[192];
    float s = (v0.x + v0.y + v0.z + v0.w) + (v1.x + v1.y + v1.z + v1.w)
            + (v2.x + v2.y + v2.z + v2.w) + (v3.x + v3.y + v3.z + v3.w);
    #pragma unroll
    for (int off = 1; off < 64; off <<= 1) s += __shfl_xor(s, off, 64);
    if (lane == 0) rs[b] = s;

    const float4* e4 = (const float4*)(emb + (size_t)id * KDIM) + lane * 4;
    float4 f0 = e4[0], f1 = e4[1], f2 = e4[2], f3 = e4[3];
    const unsigned w0 = pk4(f0, 64.f), w1 = pk4(f1, 64.f);
    const unsigned w2 = pk4(f2, 64.f), w3 = pk4(f3, 64.f);
    // swizzle m=(b&7)<<3: 16B chunk relocates by m&0x30, 8B halves swap if m&8
    uint4 val = (b & 1) ? uint4{w2, w3, w0, w1} : uint4{w0, w1, w2, w3};
    const int dst = (lane * 16) ^ (((b >> 1) & 3) << 4);
    *(uint4*)(x + (size_t)b * KDIM + dst) = val;
}

// ---------------------------------------------------------------------------
// Kernel 2: Wt[n][k] = W_{n/512}[k][n%512] * 64 fp8 e4m3, same pre-swizzle
// on k-bytes (4-byte words relocate by XOR bits 3-5; no intra-word scramble).
// ---------------------------------------------------------------------------
__global__ __launch_bounds__(256) void wconv_kernel(
    const float* __restrict__ Wq, const float* __restrict__ Ws,
    const float* __restrict__ Wk, unsigned char* __restrict__ wt)
{
    const int gt  = blockIdx.x * 256 + threadIdx.x;   // 0..393215
    const int n   = gt % NTOT;
    const int kb4 = (gt / NTOT) * 4;
    const float* W = (n < 512) ? Wq : ((n < 1024) ? Ws : Wk);
    const int nn = n & 511;
    float4 f;
    f.x = W[(size_t)(kb4 + 0) * 512 + nn];
    f.y = W[(size_t)(kb4 + 1) * 512 + nn];
    f.z = W[(size_t)(kb4 + 2) * 512 + nn];
    f.w = W[(size_t)(kb4 + 3) * 512 + nn];
    const unsigned w = pk4(f, 64.f);
    const int dst = kb4 ^ ((n & 7) << 3);
    *(unsigned*)(wt + (size_t)n * KDIM + dst) = w;
}

// ---------------------------------------------------------------------------
// Kernel 2b: csum[n] = colsum of W (fp32, deterministic).
// ---------------------------------------------------------------------------
__global__ __launch_bounds__(256) void colsum_kernel(
    const float* __restrict__ Wq, const float* __restrict__ Ws,
    const float* __restrict__ Wk, float* __restrict__ csum)
{
    const int gt = blockIdx.x * 256 + threadIdx.x;   // 0..1535
    const float* W = (gt < 512) ? Wq : ((gt < 1024) ? Ws : Wk);
    const int n = gt & 511;
    float s0 = 0.f, s1 = 0.f, s2 = 0.f, s3 = 0.f;
    #pragma unroll 4
    for (int k = 0; k < 1024; k += 4) {
        s0 += W[(size_t)(k + 0) * 512 + n];
        s1 += W[(size_t)(k + 1) * 512 + n];
        s2 += W[(size_t)(k + 2) * 512 + n];
        s3 += W[(size_t)(k + 3) * 512 + n];
    }
    csum[gt] = (s0 + s1) + (s2 + s3);
}

// ---------------------------------------------------------------------------
// Kernel 3: 256x256 8-phase fp8 GEMM (r14's race-verified skeleton, halved
// byte sizes) + rank-1 + bias + sigmoid epilogue.
//   out = sigmoid( (E@W_fp8)*2^-12 + rs*csum + bias )
//   mfma_f32_16x16x32_fp8_fp8: i64 operands, row=lane&15, k=(lane>>4)*8+[0..7]
//   (same mapping as our verified bf16 16x16x32, 1 B/elem).
//   LDS 64 KiB: {A,B} x [2 slots][2 halves][128 rows][64 B].  1 DMA instr per
//   half-tile (512 thr x 16 B = 8 KB).  Counted waits re-derived: VM2 at
//   P3/P7 -- at P3 in-flight={P1,P2,P3}, keeps newest 2, retires B10(odd
//   tile) + all older -> tile o complete before P4's post-barrier reads; at
//   P7 retires P2..P5 = tile 2t+2.  Steady state: 3 in flight entering P1.
//   WAR: every stage >=1 barrier after its region's last read was serviced.
// ---------------------------------------------------------------------------
#define BM 256
#define BN 256
#define MT (BATCH_N / BM)   // 256
#define NT (NTOT / BN)      // 6
#define NWG (MT * NT)       // 1536 = 8 * 192, 192 % 6 == 0 -> bijective

#define BAR() asm volatile("s_barrier" ::: "memory")
#define VM2() asm volatile("s_waitcnt vmcnt(2)" ::: "memory")
#define VM0() asm volatile("s_waitcnt vmcnt(0)" ::: "memory")
#define AS1 __attribute__((address_space(1)))
#define AS3 __attribute__((address_space(3)))

__global__ __launch_bounds__(512, 2) void gemm_kernel(
    const unsigned char* __restrict__ X,    // [65536][1024] fp8, swizzled
    const unsigned char* __restrict__ Wt,   // [1536][1024]  fp8, swizzled
    const float* __restrict__ csum,         // [1536]
    const float* __restrict__ rs,           // [65536]
    const float* __restrict__ bq, const float* __restrict__ bs,
    const float* __restrict__ bk, float* __restrict__ out)
{
    __shared__ __align__(16) unsigned char sA[32768];   // 32 KiB
    __shared__ __align__(16) unsigned char sB[32768];   // 32 KiB

    const int tid  = threadIdx.x;
    const int xcd  = blockIdx.x & 7;
    const int idx  = blockIdx.x >> 3;
    const int wgid = xcd * (NWG / 8) + idx;
    const int nt   = wgid % NT;              // n fastest: A-panel L2 reuse
    const int mt   = wgid / NT;
    const int m0   = mt * BM;
    const int n0   = nt * BN;
    const int wid  = tid >> 6;
    const int lane = tid & 63;
    const int wm   = wid >> 2;               // 0..1
    const int wn   = wid & 3;                // 0..3
    const int r16  = lane & 15;
    const int kb0  = (lane >> 4) << 3;       // 0,8,16,24 (bytes)
    const int ksw  = (r16 & 7) << 3;         // LDS XOR swizzle (bytes)

    f32x4 acc[8][4];
    #pragma unroll
    for (int i = 0; i < 8; i++)
        #pragma unroll
        for (int j = 0; j < 4; j++)
            acc[i][j] = f32x4{0.f, 0.f, 0.f, 0.f};

    i64 af0[4][2], af1[4][2], bfr0[2][2], bfr1[2][2];

    // staging source: row = tid>>2, 16B chunk = tid&3
    const unsigned char* gA = X  + (size_t)(m0 + (tid >> 2)) * KDIM + (tid & 3) * 16;
    const unsigned char* gB = Wt + (size_t)(n0 + (tid >> 2)) * KDIM + (tid & 3) * 16;
    const int ldst = tid * 16;               // linear LDS dest

// stage ONE half-tile (1 DMA instr/thread, 128 rows x 64 B)
#define STG_A(slot, h, kt) \
    __builtin_amdgcn_global_load_lds( \
        (const AS1 void*)(gA + (size_t)(h) * 128 * KDIM + (kt) * 64), \
        (AS3 void*)(&sA[((slot) * 2 + (h)) * 8192 + ldst]), 16, 0, 0)
#define STG_B(slot, h, kt) \
    __builtin_amdgcn_global_load_lds( \
        (const AS1 void*)(gB + (size_t)(h) * 128 * KDIM + (kt) * 64), \
        (AS3 void*)(&sB[((slot) * 2 + (h)) * 8192 + ldst]), 16, 0, 0)

#define LDA(SET, slot, qa) do {                                                 \
    const char* p = (const char*)&sA[((slot) * 2 + (qa)) * 8192];                \
    _Pragma("unroll")                                                            \
    for (int i = 0; i < 4; ++i)                                                  \
        _Pragma("unroll")                                                        \
        for (int kk = 0; kk < 2; ++kk)                                           \
            SET[i][kk] = *(const i64*)(p + (wm * 64 + i * 16 + r16) * 64         \
                                         + ((kk * 32 + kb0) ^ ksw));             \
} while (0)
#define LDB(SET, slot, qb) do {                                                 \
    const char* p = (const char*)&sB[((slot) * 2 + (qb)) * 8192];                \
    _Pragma("unroll")                                                            \
    for (int j = 0; j < 2; ++j)                                                  \
        _Pragma("unroll")                                                        \
        for (int kk = 0; kk < 2; ++kk)                                           \
            SET[j][kk] = *(const i64*)(p + (wn * 32 + j * 16 + r16) * 64         \
                                         + ((kk * 32 + kb0) ^ ksw));             \
} while (0)

#define MM(QA, QB, ASET, BSET) do {                                             \
    __builtin_amdgcn_s_setprio(1);                                               \
    _Pragma("unroll")                                                            \
    for (int i = 0; i < 4; ++i)                                                  \
        _Pragma("unroll")                                                        \
        for (int j = 0; j < 2; ++j)                                              \
            _Pragma("unroll")                                                    \
            for (int kk = 0; kk < 2; ++kk)                                       \
                acc[(QA) * 4 + i][(QB) * 2 + j] =                                \
                    __builtin_amdgcn_mfma_f32_16x16x32_fp8_fp8(                  \
                        ASET[i][kk], BSET[j][kk],                                \
                        acc[(QA) * 4 + i][(QB) * 2 + j], 0, 0, 0);               \
    __builtin_amdgcn_s_setprio(0);                                               \
} while (0)

    // ---- prologue: tile0 full (s0) + tile1 {Ah0,Bh1,Ah1} (s1) ----
    STG_A(0, 0, 0); STG_A(0, 1, 0); STG_B(0, 0, 0); STG_B(0, 1, 0);
    STG_A(1, 0, 1); STG_B(1, 1, 1); STG_A(1, 1, 1);
    VM0();
    BAR();
    LDA(af0, 0, 0); LDB(bfr0, 0, 0);         // operands for P1's MM

    // ---- main loop: 7 iterations, tiles (2t in s0, 2t+1 in s1) ----
    #pragma unroll 1
    for (int t = 0; t < 7; ++t) {
        const int ka = 2 * t + 1, kb2 = 2 * t + 2, kc = 2 * t + 3;
        // P1
        MM(0, 0, af0, bfr0);
        LDB(bfr1, 0, 1); STG_B(1, 0, ka);                        BAR();
        // P2
        MM(0, 1, af0, bfr1);
        LDA(af1, 0, 1); STG_A(0, 0, kb2);                        BAR();
        // P3
        MM(1, 1, af1, bfr1); STG_B(0, 1, kb2); VM2();            BAR();
        // P4  (s1/tile-ka reads: safe behind P3's VM2+BAR)
        MM(1, 0, af1, bfr0);
        LDA(af0, 1, 0); LDB(bfr0, 1, 0); STG_A(0, 1, kb2);       BAR();
        // P5
        MM(0, 0, af0, bfr0);
        LDB(bfr1, 1, 1); STG_B(0, 0, kb2);                       BAR();
        // P6
        MM(0, 1, af0, bfr1);
        LDA(af1, 1, 1); STG_A(1, 0, kc);                         BAR();
        // P7
        MM(1, 1, af1, bfr1); STG_B(1, 1, kc); VM2();             BAR();
        // P8  (s0/tile-kb2 reads: safe behind P7's VM2+BAR)
        MM(1, 0, af1, bfr0);
        LDA(af0, 0, 0); LDB(bfr0, 0, 0); STG_A(1, 1, kc);        BAR();
    }
    // ---- tail: tiles 14 (s0), 15 (s1) ----
    MM(0, 0, af0, bfr0);
    LDB(bfr1, 0, 1); STG_B(1, 0, 15);                            BAR();
    MM(0, 1, af0, bfr1); LDA(af1, 0, 1);                         BAR();
    MM(1, 1, af1, bfr1); VM0();                                  BAR();
    MM(1, 0, af1, bfr0); LDA(af0, 1, 0); LDB(bfr0, 1, 0);        BAR();
    MM(0, 0, af0, bfr0); LDB(bfr1, 1, 1);                        BAR();
    MM(0, 1, af0, bfr1); LDA(af1, 1, 1);                         BAR();
    MM(1, 1, af1, bfr1);                                         BAR();
    MM(1, 0, af1, bfr0);

    // ---- epilogue: acc*2^-12 + rs*csum + bias, sigmoid, NT stores ----
    // C/D layout: col=lane&15, row=(lane>>4)*4+reg  [m89/m91]
    const float inv = 1.0f / 4096.0f;               // undo 64*64 scaling
    const int grp = nt >> 1;                        // 0=q, 1=s, 2=k
    const float* bias = (grp == 0) ? bq : ((grp == 1) ? bs : bk);
    float* obase = out + (size_t)grp * ((size_t)BATCH_N * 512);
    const int cb = (nt & 1) * 256;
    #pragma unroll
    for (int qb = 0; qb < 2; ++qb)
        #pragma unroll
        for (int j = 0; j < 2; ++j) {
            const int coll = cb + qb * 128 + wn * 32 + j * 16 + r16;
            const float bv = bias[coll];
            const float cv = csum[n0 + qb * 128 + wn * 32 + j * 16 + r16];
            #pragma unroll
            for (int qa = 0; qa < 2; ++qa)
                #pragma unroll
                for (int i = 0; i < 4; ++i) {
                    const int rbase = m0 + qa * 128 + wm * 64 + i * 16 + ((lane >> 4) << 2);
                    const float4 rv = *(const float4*)(rs + rbase);
                    #pragma unroll
                    for (int r = 0; r < 4; ++r) {
                        const float rsv = (r == 0) ? rv.x : (r == 1) ? rv.y : (r == 2) ? rv.z : rv.w;
                        float v = acc[qa * 4 + i][qb * 2 + j][r] * inv + rsv * cv + bv;
                        v = 1.0f / (1.0f + __expf(-v));
                        __builtin_nontemporal_store(v, &obase[(size_t)(rbase + r) * 512 + coll]);
                    }
                }
        }
#undef STG_A
#undef STG_B
#undef LDA
#undef LDB
#undef MM
}

extern "C" void kernel_launch(void* const* d_in, const int* in_sizes, int n_in,
                              void* d_out, int out_size, void* d_ws, size_t ws_size,
                              hipStream_t stream) {
    const int*   ids = (const int*)d_in[0];
    const float* mem = (const float*)d_in[1];
    const float* emb = (const float*)d_in[2];
    const float* Wq  = (const float*)d_in[3];
    const float* bq  = (const float*)d_in[4];
    const float* Ws  = (const float*)d_in[5];
    const float* bs  = (const float*)d_in[6];
    const float* Wk  = (const float*)d_in[7];
    const float* bk  = (const float*)d_in[8];
    float* out = (float*)d_out;

    unsigned char* x  = (unsigned char*)d_ws;                 // 64 MiB fp8
    unsigned char* wt = x + (size_t)BATCH_N * KDIM;           // 1.5 MiB fp8
    float* csum = (float*)(wt + (size_t)NTOT * KDIM);         // 6 KiB
    float* rs   = csum + NTOT;                                // 256 KiB

    hipLaunchKernelGGL(wconv_kernel, dim3(NTOT), dim3(256), 0, stream, Wq, Ws, Wk, wt);
    hipLaunchKernelGGL(colsum_kernel, dim3(6), dim3(256), 0, stream, Wq, Ws, Wk, csum);
    hipLaunchKernelGGL(prep_kernel, dim3(BATCH_N / 4), dim3(256), 0, stream, ids, mem, emb, x, rs);
    hipLaunchKernelGGL(gemm_kernel, dim3(NWG), dim3(512), 0, stream,
                       x, wt, csum, rs, bq, bs, bk, out);
}